// Round 7
// baseline (171.352 us; speedup 1.0000x reference)
//
#include <hip/hip_runtime.h>
#include <math.h>

#define NB 32
#define LL 512
#define HH 1024
#define H2 512
#define DA 64

typedef unsigned int u32;
typedef unsigned short u16;
typedef __bf16 bf16x8 __attribute__((ext_vector_type(8)));
typedef float f32x4 __attribute__((ext_vector_type(4)));
typedef u16 u16x8 __attribute__((ext_vector_type(8)));

__device__ __forceinline__ u16 f2bu(float f) {          // fp32 -> bf16 bits, RNE
    u32 u = __builtin_bit_cast(u32, f);
    u = (u + 0x7fff + ((u >> 16) & 1)) >> 16;
    return (u16)u;
}

__device__ __forceinline__ float b2f(u16 u) {           // bf16 bits -> fp32
    u32 v = (u32)u << 16;
    return __builtin_bit_cast(float, v);
}

__device__ __forceinline__ void async_cp16(const void* g, void* l) {
    __builtin_amdgcn_global_load_lds(
        (const __attribute__((address_space(1))) u32*)g,
        (__attribute__((address_space(3))) u32*)l, 16, 0, 0);
}

// ========== prep: bf16 weight materialization (unchanged) ==========
__global__ void prep_kernel(const float* __restrict__ wv,
                            const float* __restrict__ kqvw,
                            const float* __restrict__ projw,
                            u16* __restrict__ wt, u16* __restrict__ kqvwT,
                            u16* __restrict__ projwT) {
    int e = blockIdx.x * 256 + threadIdx.x;
    if (e < 262144) {
        int m = e >> 9, l = e & 511;
        wt[e] = f2bu(wv[511 + m - l]);
    } else if (e < 262144 + 98304) {
        int i = e - 262144;
        int n = i >> 9, k = i & 511;
        kqvwT[i] = f2bu(kqvw[(size_t)k * 192 + n]);
    } else {
        int i = e - 360448;
        int c = i >> 6, d = i & 63;
        projwT[i] = f2bu(projw[(size_t)d * 512 + c]);
    }
}

// ========== v_kernel: fused LN-stats + affine-transpose + kqv GEMM ==========
// 512 blocks x 256 threads, 2 blocks/CU (56.5 KB LDS). 32 rows per block:
//  - A-tile = raw bf16(v), FULL 32x512 retained in LDS (low-3-bit XOR swizzle).
//  - B (kqvwT, L2-resident) double-buffered at BK=32 via swizzled global_load_lds.
//  - LN sums accumulate in-register during A staging (8 lanes per row).
//  - epilogue A: +bias, k/q/val via LDS for coalesced dumps.
//  - epilogue B: LN affine from retained A-tile -> vnT.
// Mechanism vs R6: two independent blocks per CU hide each other's barrier drains.
__global__ __launch_bounds__(256, 2)
void v_kernel(const float* __restrict__ x,
              const u16* __restrict__ kqvwT, const float* __restrict__ kqvb,
              const float* __restrict__ gamma, const float* __restrict__ beta,
              u16* __restrict__ vnT,
              u16* __restrict__ qb, u16* __restrict__ kb, u16* __restrict__ vT) {
    __shared__ u16 Af[32 * 64 * 8];             // 32 KiB: row r, abs-granule g at slot g^(r&7)
    __shared__ u16 Bs_[2][192 * 32];            // 2 x 12 KiB
    __shared__ float MU[32], RS[32];
    int blk = blockIdx.x, t = threadIdx.x;
    int R0 = blk * 32, b = R0 >> 9, l0 = R0 & 511;
    int lane = t & 63, wid = t >> 6;            // wid 0..3
    int l15 = lane & 15, q16 = lane >> 4, q8 = q16 * 8;
    int wm = (wid & 1) * 16, wn = (wid >> 1) * 96;
    const float* xg = x + (size_t)R0 * HH + H2;

    // A-stage mapping: thread t -> row = t>>3, f4 = t&7 (32 cols = 8 float4/row)
    int arow = t >> 3, af4 = t & 7;
    int sgl = af4 >> 1;                         // granule within 32-col step (0..3)
    int shalf = (af4 & 1) * 4;

    float s1 = 0.f, s2 = 0.f;
    float4 av;
    f32x4 acc[6] = {};

    // ---- prologue: issue Bs[0]; load+accumulate+write A slab 0 ----
#pragma unroll
    for (int s = 0; s < 3; ++s) {
        int ci = t + s * 256;                   // 768 chunks: 192 rows x 4 granules
        int grow = ci >> 2, gcol = ((ci & 3) ^ (grow & 3)) << 3;
        async_cp16(kqvwT + (size_t)grow * 512 + gcol, &Bs_[0][ci * 8]);
    }
    av = *(const float4*)(xg + (size_t)arow * HH + af4 * 4);
    {
        s1 += av.x + av.y + av.z + av.w;
        s2 += av.x * av.x + av.y * av.y + av.z * av.z + av.w * av.w;
        ushort4 pk;
        pk.x = f2bu(av.x); pk.y = f2bu(av.y);
        pk.z = f2bu(av.z); pk.w = f2bu(av.w);
        int slot = sgl ^ (arow & 7);            // abs granule 0*4+sgl, low-3 XOR
        *(ushort4*)(&Af[(arow * 64 + slot) * 8 + shalf]) = pk;
    }
    __syncthreads();

    // ---- 16-step pipeline (BK=32): issue next -> MFMA current -> write next A ----
    for (int it = 0; it < 16; ++it) {
        int nx = it + 1, nb = nx & 1, cb = it & 1;
        if (it < 15) {
            int k0n = nx * 32;
            av = *(const float4*)(xg + (size_t)arow * HH + k0n + af4 * 4);
#pragma unroll
            for (int s = 0; s < 3; ++s) {
                int ci = t + s * 256;
                int grow = ci >> 2, gcol = ((ci & 3) ^ (grow & 3)) << 3;
                async_cp16(kqvwT + (size_t)grow * 512 + k0n + gcol, &Bs_[nb][ci * 8]);
            }
        }
        // MFMA on current A slab + B buffer
        const u16* Bp = &Bs_[cb][0];
        {
            int row = wm + l15;
            int g = (it * 4 + q16) ^ (row & 7);
            bf16x8 a = *(const bf16x8*)(&Af[(row * 64 + g) * 8]);
#pragma unroll
            for (int j = 0; j < 6; ++j) {
                int n = wn + j * 16 + l15;
                bf16x8 bb = *(const bf16x8*)(Bp + (n * 4 + (q16 ^ (n & 3))) * 8);
                acc[j] = __builtin_amdgcn_mfma_f32_16x16x32_bf16(a, bb, acc[j], 0, 0, 0);
            }
        }
        if (it < 15) {
            s1 += av.x + av.y + av.z + av.w;
            s2 += av.x * av.x + av.y * av.y + av.z * av.z + av.w * av.w;
            ushort4 pk;
            pk.x = f2bu(av.x); pk.y = f2bu(av.y);
            pk.z = f2bu(av.z); pk.w = f2bu(av.w);
            int slot = (nx * 4 + sgl) ^ (arow & 7);
            *(ushort4*)(&Af[(arow * 64 + slot) * 8 + shalf]) = pk;
        }
        __syncthreads();
    }

    // ---- LN stats: 8-lane group reduce (8 threads per row) ----
    s1 += __shfl_xor(s1, 1); s2 += __shfl_xor(s2, 1);
    s1 += __shfl_xor(s1, 2); s2 += __shfl_xor(s2, 2);
    s1 += __shfl_xor(s1, 4); s2 += __shfl_xor(s2, 4);
    if ((t & 7) == 0) {
        float mu = s1 * (1.0f / H2);
        float rstd = rsqrtf(s2 * (1.0f / H2) - mu * mu + 1e-5f);
        MU[arow] = mu; RS[arow] = rstd;
    }

    // ---- epilogue A: +bias; k/q/val via LDS (alias Bs); coalesced dumps ----
    u16* Ks = &Bs_[0][0];                       // 32x64 = 2048 u16
    u16* Qs = &Bs_[0][2048];                    // 32x64 = 2048 u16
    u16* Vs = &Bs_[1][0];                       // 64x40 = 2560 u16 (pad 40)
    int rq = q16 * 4;
#pragma unroll
    for (int j = 0; j < 6; ++j) {
        int n = wn + j * 16 + l15;
        float bias = kqvb[n];
#pragma unroll
        for (int rr = 0; rr < 4; ++rr) {
            int m = wm + rq + rr;
            u16 hv = f2bu(acc[j][rr] + bias);
            if (n < 64)       Ks[m * 64 + n] = hv;
            else if (n < 128) Qs[m * 64 + (n - 64)] = hv;
            else              Vs[(n - 128) * 40 + m] = hv;
        }
    }
    __syncthreads();                            // also publishes MU/RS
    {
        size_t base = (size_t)R0 * 64 + t * 8;
        *(uint4*)(kb + base) = *(const uint4*)(Ks + t * 8);
        *(uint4*)(qb + base) = *(const uint4*)(Qs + t * 8);
        int d = t >> 2, ls = (t & 3) * 8;
        u16* vd = vT + ((size_t)(b * 64 + d)) * 512 + l0 + ls;
        *(uint4*)(vd) = *(const uint4*)(Vs + d * 40 + ls);
    }

    // ---- epilogue B: LN affine from Af -> vnT (2 cols/thread, 32 l each) ----
#pragma unroll
    for (int cc = 0; cc < 2; ++cc) {
        int c = t + cc * 256;
        float ga = gamma[c], be = beta[c];
        u16* d0 = vnT + ((size_t)(b * H2 + c)) * LL + l0;
        int gbase = c >> 3, coff = c & 7;
#pragma unroll
        for (int lc = 0; lc < 4; ++lc) {
            u16x8 o0;
#pragma unroll
            for (int li = 0; li < 8; ++li) {
                int l = lc * 8 + li;
                u16 w = Af[(l * 64 + (gbase ^ (l & 7))) * 8 + coff];
                o0[li] = f2bu((b2f(w) - MU[l]) * RS[l] * ga + be);
            }
            *(u16x8*)(d0 + lc * 8) = o0;
        }
    }
}

// ========== MFMA flash attention, split-K across 4 waves (unchanged) ==========
#define VLD 136
__global__ __launch_bounds__(256, 4)
void attn_kernel(const u16* __restrict__ qb, const u16* __restrict__ kb,
                 const u16* __restrict__ vT, u16* __restrict__ head) {
    __shared__ u16 Ps[4 * 16 * VLD];
    __shared__ float Osh[4][16 * 65];
    __shared__ float Msh[4][16], Lsh[4][16];
    int b = blockIdx.y, q0 = blockIdx.x * 16;
    int t = threadIdx.x, lane = t & 63, w = t >> 6;
    int l15 = lane & 15, q16 = lane >> 4, q8 = q16 * 8;
    int kc = w * 128;
    const u16* qg = qb + (size_t)b * LL * DA;
    const u16* kg = kb + (size_t)b * LL * DA;
    const u16* vg = vT + (size_t)b * DA * LL;

    bf16x8 aq[2];
#pragma unroll
    for (int s = 0; s < 2; ++s)
        aq[s] = *(const bf16x8*)(qg + (size_t)(q0 + l15) * DA + s * 32 + q8);

    f32x4 sc[8] = {};
#pragma unroll
    for (int j = 0; j < 8; ++j) {
#pragma unroll
        for (int s = 0; s < 2; ++s) {
            bf16x8 bk = *(const bf16x8*)(kg + (size_t)(kc + j * 16 + l15) * DA + s * 32 + q8);
            sc[j] = __builtin_amdgcn_mfma_f32_16x16x32_bf16(aq[s], bk, sc[j], 0, 0, 0);
        }
    }
    float mx[4], sm[4];
#pragma unroll
    for (int j = 0; j < 8; ++j)
#pragma unroll
        for (int rr = 0; rr < 4; ++rr) sc[j][rr] *= 0.125f;
#pragma unroll
    for (int rr = 0; rr < 4; ++rr) {
        float m0 = sc[0][rr];
#pragma unroll
        for (int j = 1; j < 8; ++j) m0 = fmaxf(m0, sc[j][rr]);
        m0 = fmaxf(m0, __shfl_xor(m0, 1));
        m0 = fmaxf(m0, __shfl_xor(m0, 2));
        m0 = fmaxf(m0, __shfl_xor(m0, 4));
        m0 = fmaxf(m0, __shfl_xor(m0, 8));
        mx[rr] = m0;
    }
#pragma unroll
    for (int j = 0; j < 8; ++j)
#pragma unroll
        for (int rr = 0; rr < 4; ++rr) sc[j][rr] = __expf(sc[j][rr] - mx[rr]);
#pragma unroll
    for (int rr = 0; rr < 4; ++rr) {
        float s0 = sc[0][rr];
#pragma unroll
        for (int j = 1; j < 8; ++j) s0 += sc[j][rr];
        s0 += __shfl_xor(s0, 1);
        s0 += __shfl_xor(s0, 2);
        s0 += __shfl_xor(s0, 4);
        s0 += __shfl_xor(s0, 8);
        sm[rr] = s0;
    }
    u16* Pw = Ps + w * 16 * VLD;
#pragma unroll
    for (int j = 0; j < 8; ++j)
#pragma unroll
        for (int rr = 0; rr < 4; ++rr)
            Pw[(q16 * 4 + rr) * VLD + j * 16 + l15] = f2bu(sc[j][rr]);
    f32x4 o[4] = {};
#pragma unroll
    for (int kt = 0; kt < 4; ++kt) {
        bf16x8 ap = *(const bf16x8*)(Pw + l15 * VLD + kt * 32 + q8);
#pragma unroll
        for (int j = 0; j < 4; ++j) {
            bf16x8 bv = *(const bf16x8*)(vg + (size_t)(j * 16 + l15) * LL + kc + kt * 32 + q8);
            o[j] = __builtin_amdgcn_mfma_f32_16x16x32_bf16(ap, bv, o[j], 0, 0, 0);
        }
    }
#pragma unroll
    for (int j = 0; j < 4; ++j)
#pragma unroll
        for (int rr = 0; rr < 4; ++rr)
            Osh[w][(q16 * 4 + rr) * 65 + j * 16 + l15] = o[j][rr];
    if (l15 == 0) {
#pragma unroll
        for (int rr = 0; rr < 4; ++rr) {
            Msh[w][q16 * 4 + rr] = mx[rr];
            Lsh[w][q16 * 4 + rr] = sm[rr];
        }
    }
    __syncthreads();
    int qq = t >> 4, dg = (t & 15) * 4;
    float m0 = Msh[0][qq], m1 = Msh[1][qq], m2 = Msh[2][qq], m3 = Msh[3][qq];
    float ms = fmaxf(fmaxf(m0, m1), fmaxf(m2, m3));
    float f0 = __expf(m0 - ms), f1 = __expf(m1 - ms), f2 = __expf(m2 - ms), f3 = __expf(m3 - ms);
    float lst = Lsh[0][qq] * f0 + Lsh[1][qq] * f1 + Lsh[2][qq] * f2 + Lsh[3][qq] * f3;
    float inv = 1.0f / lst;
    ushort4 res;
    u16* rp = (u16*)&res;
#pragma unroll
    for (int i = 0; i < 4; ++i) {
        int idx = qq * 65 + dg + i;
        float a = Osh[0][idx] * f0 + Osh[1][idx] * f1 + Osh[2][idx] * f2 + Osh[3][idx] * f3;
        rp[i] = f2bu(a * inv);
    }
    *(ushort4*)(head + (size_t)(b * LL + q0 + qq) * DA + dg) = res;
}

// ========== fused Toeplitz GEMM + proj + bias + gate (unchanged) ==========
__device__ __forceinline__ void mfma_tile64(const u16* As, const u16* Bs,
                                            f32x4 acc[4][4], int wm, int wn,
                                            int l15, int q16) {
    int s7 = l15 & 7;
#pragma unroll
    for (int kk = 0; kk < 2; ++kk) {
        int j0 = kk * 4 + q16;
        bf16x8 a[4], bv[4];
#pragma unroll
        for (int i = 0; i < 4; ++i) {
            int row = wm + i * 16 + l15;
            a[i] = *(const bf16x8*)(As + (row * 8 + (j0 ^ s7)) * 8);
        }
#pragma unroll
        for (int j = 0; j < 4; ++j) {
            int row = wn + j * 16 + l15;
            bv[j] = *(const bf16x8*)(Bs + (row * 8 + (j0 ^ s7)) * 8);
        }
#pragma unroll
        for (int i = 0; i < 4; ++i)
#pragma unroll
            for (int j = 0; j < 4; ++j)
                acc[i][j] = __builtin_amdgcn_mfma_f32_16x16x32_bf16(a[i], bv[j], acc[i][j], 0, 0, 0);
    }
}

__device__ __forceinline__ void stage_pair(const u16* A, const u16* B, int ldk,
                                           int koff, u16* Ad, u16* Bd, int t) {
#pragma unroll
    for (int s = 0; s < 4; ++s) {
        int ci = t + s * 256;
        int grow = ci >> 3, gcol = ((ci & 7) ^ (grow & 7)) << 3;
        async_cp16(A + (size_t)grow * ldk + koff + gcol, Ad + ci * 8);
        async_cp16(B + (size_t)grow * ldk + koff + gcol, Bd + ci * 8);
    }
}

__global__ __launch_bounds__(256, 2)
void mix_kernel(const u16* __restrict__ wt,      // [512 m][512 l]
                const u16* __restrict__ vnT,     // [B][512 c][512 l]
                const u16* __restrict__ headb,   // [B][512 m][64 d]
                const u16* __restrict__ projwT,  // [512 c][64 d]
                const float* __restrict__ x,
                const float* __restrict__ tbias,
                const float* __restrict__ projb,
                float* __restrict__ out) {
    __shared__ u16 SMEM[4][128 * 64];            // 64 KiB total (2 blk/CU)
    u16* As0 = SMEM[0]; u16* As1 = SMEM[1];
    u16* Bs0 = SMEM[2]; u16* Bs1 = SMEM[3];
    int lid = blockIdx.x;
    int p8 = lid & 7, rest = lid >> 3;
    int mi = rest & 3, pair = (rest >> 2) * 8 + p8;   // pair in [0,128)
    int b = pair >> 2, m0 = mi * 128, c0 = (pair & 3) * 128;
    int t = threadIdx.x, lane = t & 63, wid = t >> 6;
    int wm = (wid >> 1) * 64, wn = (wid & 1) * 64;
    int l15 = lane & 15, q16 = lane >> 4;
    f32x4 acc[4][4] = {};
    const u16* Ag = wt + (size_t)m0 * 512;
    const u16* Bg = vnT + ((size_t)b * H2 + c0) * 512;
    const u16* Hg = headb + ((size_t)b * LL + m0) * DA;
    const u16* Pg = projwT + (size_t)c0 * DA;

    // prologue: stage tile 0 (Toeplitz k0=0) into buf 0
    stage_pair(Ag, Bg, 512, 0, As0, Bs0, t);
    __syncthreads();                             // drains DMA

    // 9-tile pipeline: 8 Toeplitz K-slabs + proj as tile 8; stage-next ∥ MFMA-current
    for (int it = 0; it < 9; ++it) {
        int nx = it + 1;
        if (nx < 8)
            stage_pair(Ag, Bg, 512, nx * 64, (nx & 1) ? As1 : As0,
                       (nx & 1) ? Bs1 : Bs0, t);
        else if (nx == 8)
            stage_pair(Hg, Pg, 64, 0, As0, Bs0, t);
        mfma_tile64((it & 1) ? As1 : As0, (it & 1) ? Bs1 : Bs0,
                    acc, wm, wn, l15, q16);
        __syncthreads();                         // next-buf ready; cur buf released
    }

    // ---- epilogue: acc -> LDS, then streaming float4 gate pass ----
    float* Acc = (float*)&SMEM[0][0];            // 128x128 fp32 = 64 KiB exact
    int rq = q16 * 4;
#pragma unroll
    for (int i = 0; i < 4; ++i)
#pragma unroll
        for (int j = 0; j < 4; ++j)
#pragma unroll
            for (int rr = 0; rr < 4; ++rr)
                Acc[(wm + i * 16 + rq + rr) * 128 + (wn + j * 16 + l15)] = acc[i][j][rr];
    __syncthreads();
    {
        int cq = (t & 31) * 4, rg = (t >> 5) * 16;
        float4 pj = *(const float4*)(projb + c0 + cq);
#pragma unroll
        for (int rr3 = 0; rr3 < 16; ++rr3) {
            int mrow = rg + rr3;
            int m = m0 + mrow;
            float tb = tbias[m];
            float4 a4 = *(const float4*)(Acc + mrow * 128 + cq);
            float4 xv = *(const float4*)(x + ((size_t)b * LL + m) * HH + c0 + cq);
            float4 o;
            o.x = xv.x * (a4.x + tb + pj.x);
            o.y = xv.y * (a4.y + tb + pj.y);
            o.z = xv.z * (a4.z + tb + pj.z);
            o.w = xv.w * (a4.w + tb + pj.w);
            *(float4*)(out + ((size_t)b * LL + m) * H2 + c0 + cq) = o;
        }
    }
}

extern "C" void kernel_launch(void* const* d_in, const int* in_sizes, int n_in,
                              void* d_out, int out_size, void* d_ws, size_t ws_size,
                              hipStream_t stream) {
    (void)in_sizes; (void)n_in; (void)out_size; (void)ws_size;
    const float* x     = (const float*)d_in[0];
    const float* gamma = (const float*)d_in[1];
    const float* beta  = (const float*)d_in[2];
    const float* wv    = (const float*)d_in[3];
    const float* tb    = (const float*)d_in[4];
    const float* kqvw  = (const float*)d_in[5];
    const float* kqvb  = (const float*)d_in[6];
    const float* projw = (const float*)d_in[7];
    const float* projb = (const float*)d_in[8];
    float* out = (float*)d_out;

    u16* vnT_bf  = (u16*)d_ws;                          // 16 MB
    u16* qb      = vnT_bf + (size_t)NB * LL * H2;       // 2 MB
    u16* kb      = qb + (size_t)NB * LL * DA;           // 2 MB
    u16* vTb     = kb + (size_t)NB * LL * DA;           // 2 MB
    u16* head_bf = vTb + (size_t)NB * LL * DA;          // 2 MB
    u16* wt_bf   = head_bf + (size_t)NB * LL * DA;      // 512 KB
    u16* kqvwT   = wt_bf + 512 * 512;                   // 192 KB
    u16* projwT  = kqvwT + 192 * 512;                   // 64 KB

    prep_kernel <<<1536, 256, 0, stream>>>(wv, kqvw, projw, wt_bf, kqvwT, projwT);
    v_kernel    <<<512, 256, 0, stream>>>(x, kqvwT, kqvb, gamma, beta,
                                          vnT_bf, qb, kb, vTb);
    attn_kernel <<<dim3(32, NB), 256, 0, stream>>>(qb, kb, vTb, head_bf);
    mix_kernel  <<<512, 256, 0, stream>>>(wt_bf, vnT_bf, head_bf, projwT,
                                          x, tb, projb, out);
}

// Round 8
// 169.363 us; speedup vs baseline: 1.0117x; 1.0117x over previous
//
#include <hip/hip_runtime.h>
#include <math.h>

#define NB 32
#define LL 512
#define HH 1024
#define H2 512
#define DA 64

typedef unsigned int u32;
typedef unsigned short u16;
typedef __bf16 bf16x8 __attribute__((ext_vector_type(8)));
typedef float f32x4 __attribute__((ext_vector_type(4)));
typedef u16 u16x8 __attribute__((ext_vector_type(8)));

__device__ __forceinline__ u16 f2bu(float f) {          // fp32 -> bf16 bits, RNE
    u32 u = __builtin_bit_cast(u32, f);
    u = (u + 0x7fff + ((u >> 16) & 1)) >> 16;
    return (u16)u;
}

__device__ __forceinline__ float b2f(u16 u) {           // bf16 bits -> fp32
    u32 v = (u32)u << 16;
    return __builtin_bit_cast(float, v);
}

__device__ __forceinline__ void async_cp16(const void* g, void* l) {
    __builtin_amdgcn_global_load_lds(
        (const __attribute__((address_space(1))) u32*)g,
        (__attribute__((address_space(3))) u32*)l, 16, 0, 0);
}

// ========== prep: bf16 weight materialization (unchanged) ==========
__global__ void prep_kernel(const float* __restrict__ wv,
                            const float* __restrict__ kqvw,
                            const float* __restrict__ projw,
                            u16* __restrict__ wt, u16* __restrict__ kqvwT,
                            u16* __restrict__ projwT) {
    int e = blockIdx.x * 256 + threadIdx.x;
    if (e < 262144) {
        int m = e >> 9, l = e & 511;
        wt[e] = f2bu(wv[511 + m - l]);
    } else if (e < 262144 + 98304) {
        int i = e - 262144;
        int n = i >> 9, k = i & 511;
        kqvwT[i] = f2bu(kqvw[(size_t)k * 192 + n]);
    } else {
        int i = e - 360448;
        int c = i >> 6, d = i & 63;
        projwT[i] = f2bu(projw[(size_t)d * 512 + c]);
    }
}

// ========== v_kernel: deep-upfront-load LN + kqv GEMM ==========
// 512 blocks x 512 threads (32 rows/block); LDS exactly 80 KiB -> 2 blocks/CU
// (16 waves/CU). Little's-law fix: 8 independent float4 x-loads per lane
// (128 B/lane in flight) + B0 stage issued before ONE barrier; GEMM is only
// 8 BK=64 rounds. LN stats ride the registers; MU/RS parked in the dead B
// buffer after the loop so LDS stays at 80 KiB.
__global__ __launch_bounds__(512, 4)
void v_kernel(const float* __restrict__ x,
              const u16* __restrict__ kqvwT, const float* __restrict__ kqvb,
              const float* __restrict__ gamma, const float* __restrict__ beta,
              u16* __restrict__ vnT,
              u16* __restrict__ qb, u16* __restrict__ kb, u16* __restrict__ vT) {
    __shared__ u16 Af[32 * 64 * 8];             // 32 KiB: row r, abs-granule g at slot g^(r&7)
    __shared__ u16 Bs_[2][192 * 64];            // 2 x 24 KiB (total with Af = 80 KiB exact)
    int blk = blockIdx.x, t = threadIdx.x;
    int R0 = blk * 32, b = R0 >> 9, l0 = R0 & 511;
    int lane = t & 63, wid = t >> 6;            // wid 0..7
    int l15 = lane & 15, q16 = lane >> 4;
    int wm = (wid & 1) * 16, wn = (wid >> 1) * 48;
    const float* xg = x + (size_t)R0 * HH + H2;

    // ---- prologue: issue B0 stage + ALL 8 x float4 loads, then convert ----
#pragma unroll
    for (int s = 0; s < 3; ++s) {
        int ci = t + s * 512;                   // 1536 granules: 192 rows x 8
        int grow = ci >> 3, gcol = ((ci & 7) ^ (grow & 7)) << 3;
        async_cp16(kqvwT + (size_t)grow * 512 + gcol, &Bs_[0][ci * 8]);
    }
    int row = t >> 4, seg = t & 15;             // 32 rows x 16 segments of 32 cols
    const float* xr = xg + (size_t)row * HH + seg * 32;
    float4 xv[8];
#pragma unroll
    for (int i = 0; i < 8; ++i) xv[i] = *(const float4*)(xr + i * 4);

    float s1 = 0.f, s2 = 0.f;
    int r7 = row & 7;
#pragma unroll
    for (int i = 0; i < 8; ++i) {
        float4 v = xv[i];
        s1 += v.x + v.y + v.z + v.w;
        s2 += v.x * v.x + v.y * v.y + v.z * v.z + v.w * v.w;
        int g = seg * 4 + (i >> 1);             // abs granule 0..63
        int slot = g ^ r7;
        ushort4 pk;
        pk.x = f2bu(v.x); pk.y = f2bu(v.y);
        pk.z = f2bu(v.z); pk.w = f2bu(v.w);
        *(ushort4*)(&Af[(row * 64 + slot) * 8 + (i & 1) * 4]) = pk;
    }
    __syncthreads();                            // Af ready; B0 DMA drained

    // ---- GEMM: 8 rounds of BK=64; stage-next || MFMA-current ----
    f32x4 acc[3] = {};
    int rowA = wm + l15, rA7 = rowA & 7;
    for (int it = 0; it < 8; ++it) {
        int cb = it & 1;
        if (it < 7) {
            int k0n = (it + 1) * 64;
#pragma unroll
            for (int s = 0; s < 3; ++s) {
                int ci = t + s * 512;
                int grow = ci >> 3, gcol = ((ci & 7) ^ (grow & 7)) << 3;
                async_cp16(kqvwT + (size_t)grow * 512 + k0n + gcol,
                           &Bs_[cb ^ 1][ci * 8]);
            }
        }
        const u16* Bp = &Bs_[cb][0];
#pragma unroll
        for (int kk = 0; kk < 2; ++kk) {
            int j0 = kk * 4 + q16;
            int g = (it * 8 + j0) ^ rA7;
            bf16x8 a = *(const bf16x8*)(&Af[(rowA * 64 + g) * 8]);
#pragma unroll
            for (int j = 0; j < 3; ++j) {
                int n = wn + j * 16 + l15;
                bf16x8 bb = *(const bf16x8*)(Bp + (n * 8 + (j0 ^ (n & 7))) * 8);
                acc[j] = __builtin_amdgcn_mfma_f32_16x16x32_bf16(a, bb, acc[j], 0, 0, 0);
            }
        }
        __syncthreads();
    }

    // ---- LN stats: 16-lane row-group reduce; publish into dead B buffer ----
    s1 += __shfl_xor(s1, 1); s2 += __shfl_xor(s2, 1);
    s1 += __shfl_xor(s1, 2); s2 += __shfl_xor(s2, 2);
    s1 += __shfl_xor(s1, 4); s2 += __shfl_xor(s2, 4);
    s1 += __shfl_xor(s1, 8); s2 += __shfl_xor(s2, 8);
    float* MU = (float*)(&Bs_[1][8192]);        // bytes 16384.. of Bs_[1] (Vs uses 0..5120)
    float* RS = MU + 32;
    if ((t & 15) == 0) {
        float mu = s1 * (1.0f / H2);
        float rstd = rsqrtf(s2 * (1.0f / H2) - mu * mu + 1e-5f);
        MU[row] = mu; RS[row] = rstd;
    }

    // ---- epilogue A: +bias; k/q/val via LDS (alias Bs); coalesced dumps ----
    u16* Ks = &Bs_[0][0];                       // 32x64 = 2048 u16
    u16* Qs = &Bs_[0][2048];                    // 32x64 = 2048 u16
    u16* Vs = &Bs_[1][0];                       // 64x40 = 2560 u16 (pad 40)
    int rq = q16 * 4;
#pragma unroll
    for (int j = 0; j < 3; ++j) {
        int n = wn + j * 16 + l15;
        float bias = kqvb[n];
#pragma unroll
        for (int rr = 0; rr < 4; ++rr) {
            int m = wm + rq + rr;
            u16 hv = f2bu(acc[j][rr] + bias);
            if (n < 64)       Ks[m * 64 + n] = hv;
            else if (n < 128) Qs[m * 64 + (n - 64)] = hv;
            else              Vs[(n - 128) * 40 + m] = hv;
        }
    }
    __syncthreads();                            // publishes Ks/Qs/Vs + MU/RS
    if (t < 256) {
        *(uint4*)(kb + (size_t)R0 * 64 + t * 8) = *(const uint4*)(Ks + t * 8);
    } else {
        int u = t - 256;
        *(uint4*)(qb + (size_t)R0 * 64 + u * 8) = *(const uint4*)(Qs + u * 8);
    }
    {
        int d = t >> 3, ls = (t & 7) * 4;
        *(ushort4*)(vT + ((size_t)(b * 64 + d)) * 512 + l0 + ls) =
            *(const ushort4*)(Vs + d * 40 + ls);
    }

    // ---- epilogue B: LN affine from Af -> vnT (1 col/thread, 32 l each) ----
    {
        int c = t;
        float ga = gamma[c], be = beta[c];
        u16* d0 = vnT + ((size_t)(b * H2 + c)) * LL + l0;
        int gbase = c >> 3, coff = c & 7;
#pragma unroll
        for (int lc = 0; lc < 4; ++lc) {
            u16x8 o0;
#pragma unroll
            for (int li = 0; li < 8; ++li) {
                int l = lc * 8 + li;
                u16 w = Af[(l * 64 + (gbase ^ (l & 7))) * 8 + coff];
                o0[li] = f2bu((b2f(w) - MU[l]) * RS[l] * ga + be);
            }
            *(u16x8*)(d0 + lc * 8) = o0;
        }
    }
}

// ========== MFMA flash attention, split-K across 4 waves (unchanged) ==========
#define VLD 136
__global__ __launch_bounds__(256, 4)
void attn_kernel(const u16* __restrict__ qb, const u16* __restrict__ kb,
                 const u16* __restrict__ vT, u16* __restrict__ head) {
    __shared__ u16 Ps[4 * 16 * VLD];
    __shared__ float Osh[4][16 * 65];
    __shared__ float Msh[4][16], Lsh[4][16];
    int b = blockIdx.y, q0 = blockIdx.x * 16;
    int t = threadIdx.x, lane = t & 63, w = t >> 6;
    int l15 = lane & 15, q16 = lane >> 4, q8 = q16 * 8;
    int kc = w * 128;
    const u16* qg = qb + (size_t)b * LL * DA;
    const u16* kg = kb + (size_t)b * LL * DA;
    const u16* vg = vT + (size_t)b * DA * LL;

    bf16x8 aq[2];
#pragma unroll
    for (int s = 0; s < 2; ++s)
        aq[s] = *(const bf16x8*)(qg + (size_t)(q0 + l15) * DA + s * 32 + q8);

    f32x4 sc[8] = {};
#pragma unroll
    for (int j = 0; j < 8; ++j) {
#pragma unroll
        for (int s = 0; s < 2; ++s) {
            bf16x8 bk = *(const bf16x8*)(kg + (size_t)(kc + j * 16 + l15) * DA + s * 32 + q8);
            sc[j] = __builtin_amdgcn_mfma_f32_16x16x32_bf16(aq[s], bk, sc[j], 0, 0, 0);
        }
    }
    float mx[4], sm[4];
#pragma unroll
    for (int j = 0; j < 8; ++j)
#pragma unroll
        for (int rr = 0; rr < 4; ++rr) sc[j][rr] *= 0.125f;
#pragma unroll
    for (int rr = 0; rr < 4; ++rr) {
        float m0 = sc[0][rr];
#pragma unroll
        for (int j = 1; j < 8; ++j) m0 = fmaxf(m0, sc[j][rr]);
        m0 = fmaxf(m0, __shfl_xor(m0, 1));
        m0 = fmaxf(m0, __shfl_xor(m0, 2));
        m0 = fmaxf(m0, __shfl_xor(m0, 4));
        m0 = fmaxf(m0, __shfl_xor(m0, 8));
        mx[rr] = m0;
    }
#pragma unroll
    for (int j = 0; j < 8; ++j)
#pragma unroll
        for (int rr = 0; rr < 4; ++rr) sc[j][rr] = __expf(sc[j][rr] - mx[rr]);
#pragma unroll
    for (int rr = 0; rr < 4; ++rr) {
        float s0 = sc[0][rr];
#pragma unroll
        for (int j = 1; j < 8; ++j) s0 += sc[j][rr];
        s0 += __shfl_xor(s0, 1);
        s0 += __shfl_xor(s0, 2);
        s0 += __shfl_xor(s0, 4);
        s0 += __shfl_xor(s0, 8);
        sm[rr] = s0;
    }
    u16* Pw = Ps + w * 16 * VLD;
#pragma unroll
    for (int j = 0; j < 8; ++j)
#pragma unroll
        for (int rr = 0; rr < 4; ++rr)
            Pw[(q16 * 4 + rr) * VLD + j * 16 + l15] = f2bu(sc[j][rr]);
    f32x4 o[4] = {};
#pragma unroll
    for (int kt = 0; kt < 4; ++kt) {
        bf16x8 ap = *(const bf16x8*)(Pw + l15 * VLD + kt * 32 + q8);
#pragma unroll
        for (int j = 0; j < 4; ++j) {
            bf16x8 bv = *(const bf16x8*)(vg + (size_t)(j * 16 + l15) * LL + kc + kt * 32 + q8);
            o[j] = __builtin_amdgcn_mfma_f32_16x16x32_bf16(ap, bv, o[j], 0, 0, 0);
        }
    }
#pragma unroll
    for (int j = 0; j < 4; ++j)
#pragma unroll
        for (int rr = 0; rr < 4; ++rr)
            Osh[w][(q16 * 4 + rr) * 65 + j * 16 + l15] = o[j][rr];
    if (l15 == 0) {
#pragma unroll
        for (int rr = 0; rr < 4; ++rr) {
            Msh[w][q16 * 4 + rr] = mx[rr];
            Lsh[w][q16 * 4 + rr] = sm[rr];
        }
    }
    __syncthreads();
    int qq = t >> 4, dg = (t & 15) * 4;
    float m0 = Msh[0][qq], m1 = Msh[1][qq], m2 = Msh[2][qq], m3 = Msh[3][qq];
    float ms = fmaxf(fmaxf(m0, m1), fmaxf(m2, m3));
    float f0 = __expf(m0 - ms), f1 = __expf(m1 - ms), f2 = __expf(m2 - ms), f3 = __expf(m3 - ms);
    float lst = Lsh[0][qq] * f0 + Lsh[1][qq] * f1 + Lsh[2][qq] * f2 + Lsh[3][qq] * f3;
    float inv = 1.0f / lst;
    ushort4 res;
    u16* rp = (u16*)&res;
#pragma unroll
    for (int i = 0; i < 4; ++i) {
        int idx = qq * 65 + dg + i;
        float a = Osh[0][idx] * f0 + Osh[1][idx] * f1 + Osh[2][idx] * f2 + Osh[3][idx] * f3;
        rp[i] = f2bu(a * inv);
    }
    *(ushort4*)(head + (size_t)(b * LL + q0 + qq) * DA + dg) = res;
}

// ========== fused Toeplitz GEMM + proj + bias + gate (unchanged) ==========
__device__ __forceinline__ void mfma_tile64(const u16* As, const u16* Bs,
                                            f32x4 acc[4][4], int wm, int wn,
                                            int l15, int q16) {
    int s7 = l15 & 7;
#pragma unroll
    for (int kk = 0; kk < 2; ++kk) {
        int j0 = kk * 4 + q16;
        bf16x8 a[4], bv[4];
#pragma unroll
        for (int i = 0; i < 4; ++i) {
            int row = wm + i * 16 + l15;
            a[i] = *(const bf16x8*)(As + (row * 8 + (j0 ^ s7)) * 8);
        }
#pragma unroll
        for (int j = 0; j < 4; ++j) {
            int row = wn + j * 16 + l15;
            bv[j] = *(const bf16x8*)(Bs + (row * 8 + (j0 ^ s7)) * 8);
        }
#pragma unroll
        for (int i = 0; i < 4; ++i)
#pragma unroll
            for (int j = 0; j < 4; ++j)
                acc[i][j] = __builtin_amdgcn_mfma_f32_16x16x32_bf16(a[i], bv[j], acc[i][j], 0, 0, 0);
    }
}

__device__ __forceinline__ void stage_pair(const u16* A, const u16* B, int ldk,
                                           int koff, u16* Ad, u16* Bd, int t) {
#pragma unroll
    for (int s = 0; s < 4; ++s) {
        int ci = t + s * 256;
        int grow = ci >> 3, gcol = ((ci & 7) ^ (grow & 7)) << 3;
        async_cp16(A + (size_t)grow * ldk + koff + gcol, Ad + ci * 8);
        async_cp16(B + (size_t)grow * ldk + koff + gcol, Bd + ci * 8);
    }
}

__global__ __launch_bounds__(256, 2)
void mix_kernel(const u16* __restrict__ wt,      // [512 m][512 l]
                const u16* __restrict__ vnT,     // [B][512 c][512 l]
                const u16* __restrict__ headb,   // [B][512 m][64 d]
                const u16* __restrict__ projwT,  // [512 c][64 d]
                const float* __restrict__ x,
                const float* __restrict__ tbias,
                const float* __restrict__ projb,
                float* __restrict__ out) {
    __shared__ u16 SMEM[4][128 * 64];            // 64 KiB total (2 blk/CU)
    u16* As0 = SMEM[0]; u16* As1 = SMEM[1];
    u16* Bs0 = SMEM[2]; u16* Bs1 = SMEM[3];
    int lid = blockIdx.x;
    int p8 = lid & 7, rest = lid >> 3;
    int mi = rest & 3, pair = (rest >> 2) * 8 + p8;   // pair in [0,128)
    int b = pair >> 2, m0 = mi * 128, c0 = (pair & 3) * 128;
    int t = threadIdx.x, lane = t & 63, wid = t >> 6;
    int wm = (wid >> 1) * 64, wn = (wid & 1) * 64;
    int l15 = lane & 15, q16 = lane >> 4;
    f32x4 acc[4][4] = {};
    const u16* Ag = wt + (size_t)m0 * 512;
    const u16* Bg = vnT + ((size_t)b * H2 + c0) * 512;
    const u16* Hg = headb + ((size_t)b * LL + m0) * DA;
    const u16* Pg = projwT + (size_t)c0 * DA;

    // prologue: stage tile 0 (Toeplitz k0=0) into buf 0
    stage_pair(Ag, Bg, 512, 0, As0, Bs0, t);
    __syncthreads();                             // drains DMA

    // 9-tile pipeline: 8 Toeplitz K-slabs + proj as tile 8; stage-next ∥ MFMA-current
    for (int it = 0; it < 9; ++it) {
        int nx = it + 1;
        if (nx < 8)
            stage_pair(Ag, Bg, 512, nx * 64, (nx & 1) ? As1 : As0,
                       (nx & 1) ? Bs1 : Bs0, t);
        else if (nx == 8)
            stage_pair(Hg, Pg, 64, 0, As0, Bs0, t);
        mfma_tile64((it & 1) ? As1 : As0, (it & 1) ? Bs1 : Bs0,
                    acc, wm, wn, l15, q16);
        __syncthreads();                         // next-buf ready; cur buf released
    }

    // ---- epilogue: acc -> LDS, then streaming float4 gate pass ----
    float* Acc = (float*)&SMEM[0][0];            // 128x128 fp32 = 64 KiB exact
    int rq = q16 * 4;
#pragma unroll
    for (int i = 0; i < 4; ++i)
#pragma unroll
        for (int j = 0; j < 4; ++j)
#pragma unroll
            for (int rr = 0; rr < 4; ++rr)
                Acc[(wm + i * 16 + rq + rr) * 128 + (wn + j * 16 + l15)] = acc[i][j][rr];
    __syncthreads();
    {
        int cq = (t & 31) * 4, rg = (t >> 5) * 16;
        float4 pj = *(const float4*)(projb + c0 + cq);
#pragma unroll
        for (int rr3 = 0; rr3 < 16; ++rr3) {
            int mrow = rg + rr3;
            int m = m0 + mrow;
            float tb = tbias[m];
            float4 a4 = *(const float4*)(Acc + mrow * 128 + cq);
            float4 xv = *(const float4*)(x + ((size_t)b * LL + m) * HH + c0 + cq);
            float4 o;
            o.x = xv.x * (a4.x + tb + pj.x);
            o.y = xv.y * (a4.y + tb + pj.y);
            o.z = xv.z * (a4.z + tb + pj.z);
            o.w = xv.w * (a4.w + tb + pj.w);
            *(float4*)(out + ((size_t)b * LL + m) * H2 + c0 + cq) = o;
        }
    }
}

extern "C" void kernel_launch(void* const* d_in, const int* in_sizes, int n_in,
                              void* d_out, int out_size, void* d_ws, size_t ws_size,
                              hipStream_t stream) {
    (void)in_sizes; (void)n_in; (void)out_size; (void)ws_size;
    const float* x     = (const float*)d_in[0];
    const float* gamma = (const float*)d_in[1];
    const float* beta  = (const float*)d_in[2];
    const float* wv    = (const float*)d_in[3];
    const float* tb    = (const float*)d_in[4];
    const float* kqvw  = (const float*)d_in[5];
    const float* kqvb  = (const float*)d_in[6];
    const float* projw = (const float*)d_in[7];
    const float* projb = (const float*)d_in[8];
    float* out = (float*)d_out;

    u16* vnT_bf  = (u16*)d_ws;                          // 16 MB
    u16* qb      = vnT_bf + (size_t)NB * LL * H2;       // 2 MB
    u16* kb      = qb + (size_t)NB * LL * DA;           // 2 MB
    u16* vTb     = kb + (size_t)NB * LL * DA;           // 2 MB
    u16* head_bf = vTb + (size_t)NB * LL * DA;          // 2 MB
    u16* wt_bf   = head_bf + (size_t)NB * LL * DA;      // 512 KB
    u16* kqvwT   = wt_bf + 512 * 512;                   // 192 KB
    u16* projwT  = kqvwT + 192 * 512;                   // 64 KB

    prep_kernel <<<1536, 256, 0, stream>>>(wv, kqvw, projw, wt_bf, kqvwT, projwT);
    v_kernel    <<<512, 512, 0, stream>>>(x, kqvwT, kqvb, gamma, beta,
                                          vnT_bf, qb, kb, vTb);
    attn_kernel <<<dim3(32, NB), 256, 0, stream>>>(qb, kb, vTb, head_bf);
    mix_kernel  <<<512, 256, 0, stream>>>(wt_bf, vnT_bf, head_bf, projwT,
                                          x, tb, projb, out);
}

// Round 9
// 166.266 us; speedup vs baseline: 1.0306x; 1.0186x over previous
//
#include <hip/hip_runtime.h>
#include <math.h>

#define NB 32
#define LL 512
#define HH 1024
#define H2 512
#define DA 64

typedef unsigned int u32;
typedef unsigned short u16;
typedef __bf16 bf16x8 __attribute__((ext_vector_type(8)));
typedef float f32x4 __attribute__((ext_vector_type(4)));
typedef u16 u16x8 __attribute__((ext_vector_type(8)));

__device__ __forceinline__ u16 f2bu(float f) {          // fp32 -> bf16 bits, RNE
    u32 u = __builtin_bit_cast(u32, f);
    u = (u + 0x7fff + ((u >> 16) & 1)) >> 16;
    return (u16)u;
}

__device__ __forceinline__ float b2f(u16 u) {           // bf16 bits -> fp32
    u32 v = (u32)u << 16;
    return __builtin_bit_cast(float, v);
}

__device__ __forceinline__ void async_cp16(const void* g, void* l) {
    __builtin_amdgcn_global_load_lds(
        (const __attribute__((address_space(1))) u32*)g,
        (__attribute__((address_space(3))) u32*)l, 16, 0, 0);
}

// ========== prep: bf16 weight materialization (unchanged) ==========
__global__ void prep_kernel(const float* __restrict__ wv,
                            const float* __restrict__ kqvw,
                            const float* __restrict__ projw,
                            u16* __restrict__ wt, u16* __restrict__ kqvwT,
                            u16* __restrict__ projwT) {
    int e = blockIdx.x * 256 + threadIdx.x;
    if (e < 262144) {
        int m = e >> 9, l = e & 511;
        wt[e] = f2bu(wv[511 + m - l]);
    } else if (e < 262144 + 98304) {
        int i = e - 262144;
        int n = i >> 9, k = i & 511;
        kqvwT[i] = f2bu(kqvw[(size_t)k * 192 + n]);
    } else {
        int i = e - 360448;
        int c = i >> 6, d = i & 63;
        projwT[i] = f2bu(projw[(size_t)d * 512 + c]);
    }
}

// ========== v_kernel: R6 geometry + R8 deep-upfront prologue ==========
// 256 blocks x 512 threads, 64 rows/block, 1 blk/CU (112 KiB LDS), 8 waves.
// B traffic: 256 x 192 KB = 49 MB (R8's 512-block variant paid 98 MB).
// Prologue: issue B0 stage + ALL 16 float4 x-loads per lane (256 B in flight),
// convert/write the full 64x512 Af tile, LN sums in-reg, ONE barrier.
// GEMM: 8 BK=64 rounds, wave tile 16x96, dbuf B, per-round chain is only
// {3 cp16 -> 12 MFMA -> barrier}. MU/RS parked in dead B buffer post-loop.
__global__ __launch_bounds__(512, 1)
void v_kernel(const float* __restrict__ x,
              const u16* __restrict__ kqvwT, const float* __restrict__ kqvb,
              const float* __restrict__ gamma, const float* __restrict__ beta,
              u16* __restrict__ vnT,
              u16* __restrict__ qb, u16* __restrict__ kb, u16* __restrict__ vT) {
    __shared__ u16 Af[64 * 64 * 8];             // 64 KiB: row r, abs-granule g at slot g^(r&7)
    __shared__ u16 Bs_[2][192 * 64];            // 2 x 24 KiB
    int blk = blockIdx.x, t = threadIdx.x;
    int R0 = blk * 64, b = R0 >> 9, l0 = R0 & 511;
    int lane = t & 63, wid = t >> 6;            // wid 0..7
    int l15 = lane & 15, q16 = lane >> 4;
    int wm = (wid & 3) * 16, wn = (wid >> 2) * 96;
    const float* xg = x + (size_t)R0 * HH + H2;

    // ---- prologue: issue B0 stage, then ALL 16 x float4 loads, then convert ----
#pragma unroll
    for (int s = 0; s < 3; ++s) {
        int ci = t + s * 512;                   // 1536 granules: 192 rows x 8
        int grow = ci >> 3, gcol = ((ci & 7) ^ (grow & 7)) << 3;
        async_cp16(kqvwT + (size_t)grow * 512 + gcol, &Bs_[0][ci * 8]);
    }
    int row = t >> 3, c64 = (t & 7) * 64;       // 64 rows x 8 threads; 64 cols each
    const float* xr = xg + (size_t)row * HH + c64;
    float4 xv[16];
#pragma unroll
    for (int i = 0; i < 16; ++i) xv[i] = *(const float4*)(xr + i * 4);

    float s1 = 0.f, s2 = 0.f;
    int r7 = row & 7;
#pragma unroll
    for (int i = 0; i < 16; ++i) {
        float4 v = xv[i];
        s1 += v.x + v.y + v.z + v.w;
        s2 += v.x * v.x + v.y * v.y + v.z * v.z + v.w * v.w;
        int g = (c64 >> 3) + (i >> 1);          // abs granule 0..63
        int slot = g ^ r7;
        ushort4 pk;
        pk.x = f2bu(v.x); pk.y = f2bu(v.y);
        pk.z = f2bu(v.z); pk.w = f2bu(v.w);
        *(ushort4*)(&Af[(row * 64 + slot) * 8 + (i & 1) * 4]) = pk;
    }
    __syncthreads();                            // Af ready; B0 DMA drained

    // ---- GEMM: 8 rounds of BK=64; stage-next || MFMA-current ----
    f32x4 acc[6] = {};
    int rowA = wm + l15, rA7 = rowA & 7;
    for (int it = 0; it < 8; ++it) {
        int cb = it & 1;
        if (it < 7) {
            int k0n = (it + 1) * 64;
#pragma unroll
            for (int s = 0; s < 3; ++s) {
                int ci = t + s * 512;
                int grow = ci >> 3, gcol = ((ci & 7) ^ (grow & 7)) << 3;
                async_cp16(kqvwT + (size_t)grow * 512 + k0n + gcol,
                           &Bs_[cb ^ 1][ci * 8]);
            }
        }
        const u16* Bp = &Bs_[cb][0];
#pragma unroll
        for (int kk = 0; kk < 2; ++kk) {
            int j0 = kk * 4 + q16;
            int g = (it * 8 + j0) ^ rA7;
            bf16x8 a = *(const bf16x8*)(&Af[(rowA * 64 + g) * 8]);
#pragma unroll
            for (int j = 0; j < 6; ++j) {
                int n = wn + j * 16 + l15;
                bf16x8 bb = *(const bf16x8*)(Bp + (n * 8 + (j0 ^ (n & 7))) * 8);
                acc[j] = __builtin_amdgcn_mfma_f32_16x16x32_bf16(a, bb, acc[j], 0, 0, 0);
            }
        }
        __syncthreads();
    }

    // ---- LN stats: 8-lane row-group reduce; publish into dead B buffer ----
    s1 += __shfl_xor(s1, 1); s2 += __shfl_xor(s2, 1);
    s1 += __shfl_xor(s1, 2); s2 += __shfl_xor(s2, 2);
    s1 += __shfl_xor(s1, 4); s2 += __shfl_xor(s2, 4);
    float* MU = (float*)(&Bs_[1][8192]);        // Bs_[1] u16 idx 8192.. (Vs uses 0..4608)
    float* RS = MU + 64;
    if ((t & 7) == 0) {
        float mu = s1 * (1.0f / H2);
        float rstd = rsqrtf(s2 * (1.0f / H2) - mu * mu + 1e-5f);
        MU[row] = mu; RS[row] = rstd;
    }

    // ---- epilogue A: +bias; k/q/val via LDS (alias Bs); coalesced dumps ----
    u16* Ks = &Bs_[0][0];                       // 64x64 = 4096 u16
    u16* Qs = &Bs_[0][4096];                    // 64x64 = 4096 u16
    u16* Vs = &Bs_[1][0];                       // 64x72 = 4608 u16 (pad 72)
    int rq = q16 * 4;
#pragma unroll
    for (int j = 0; j < 6; ++j) {
        int n = wn + j * 16 + l15;
        float bias = kqvb[n];
#pragma unroll
        for (int rr = 0; rr < 4; ++rr) {
            int m = wm + rq + rr;
            u16 hv = f2bu(acc[j][rr] + bias);
            if (n < 64)       Ks[m * 64 + n] = hv;
            else if (n < 128) Qs[m * 64 + (n - 64)] = hv;
            else              Vs[(n - 128) * 72 + m] = hv;
        }
    }
    __syncthreads();                            // publishes Ks/Qs/Vs + MU/RS
    {
        size_t base = (size_t)R0 * 64 + t * 8;
        *(uint4*)(kb + base) = *(const uint4*)(Ks + t * 8);
        *(uint4*)(qb + base) = *(const uint4*)(Qs + t * 8);
        int d = t >> 3, ls = (t & 7) * 8;
        *(uint4*)(vT + ((size_t)(b * 64 + d)) * 512 + l0 + ls) =
            *(const uint4*)(Vs + d * 72 + ls);
    }

    // ---- epilogue B: LN affine from Af -> vnT (1 col/thread, 64 l each) ----
    {
        int c = t;
        float ga = gamma[c], be = beta[c];
        u16* d0 = vnT + ((size_t)(b * H2 + c)) * LL + l0;
        int gbase = c >> 3, coff = c & 7;
#pragma unroll
        for (int lc = 0; lc < 8; ++lc) {
            u16x8 o0;
#pragma unroll
            for (int li = 0; li < 8; ++li) {
                int l = lc * 8 + li;
                u16 w = Af[(l * 64 + (gbase ^ (l & 7))) * 8 + coff];
                o0[li] = f2bu((b2f(w) - MU[l]) * RS[l] * ga + be);
            }
            *(u16x8*)(d0 + lc * 8) = o0;
        }
    }
}

// ========== MFMA flash attention, split-K across 4 waves (unchanged) ==========
#define VLD 136
__global__ __launch_bounds__(256, 4)
void attn_kernel(const u16* __restrict__ qb, const u16* __restrict__ kb,
                 const u16* __restrict__ vT, u16* __restrict__ head) {
    __shared__ u16 Ps[4 * 16 * VLD];
    __shared__ float Osh[4][16 * 65];
    __shared__ float Msh[4][16], Lsh[4][16];
    int b = blockIdx.y, q0 = blockIdx.x * 16;
    int t = threadIdx.x, lane = t & 63, w = t >> 6;
    int l15 = lane & 15, q16 = lane >> 4, q8 = q16 * 8;
    int kc = w * 128;
    const u16* qg = qb + (size_t)b * LL * DA;
    const u16* kg = kb + (size_t)b * LL * DA;
    const u16* vg = vT + (size_t)b * DA * LL;

    bf16x8 aq[2];
#pragma unroll
    for (int s = 0; s < 2; ++s)
        aq[s] = *(const bf16x8*)(qg + (size_t)(q0 + l15) * DA + s * 32 + q8);

    f32x4 sc[8] = {};
#pragma unroll
    for (int j = 0; j < 8; ++j) {
#pragma unroll
        for (int s = 0; s < 2; ++s) {
            bf16x8 bk = *(const bf16x8*)(kg + (size_t)(kc + j * 16 + l15) * DA + s * 32 + q8);
            sc[j] = __builtin_amdgcn_mfma_f32_16x16x32_bf16(aq[s], bk, sc[j], 0, 0, 0);
        }
    }
    float mx[4], sm[4];
#pragma unroll
    for (int j = 0; j < 8; ++j)
#pragma unroll
        for (int rr = 0; rr < 4; ++rr) sc[j][rr] *= 0.125f;
#pragma unroll
    for (int rr = 0; rr < 4; ++rr) {
        float m0 = sc[0][rr];
#pragma unroll
        for (int j = 1; j < 8; ++j) m0 = fmaxf(m0, sc[j][rr]);
        m0 = fmaxf(m0, __shfl_xor(m0, 1));
        m0 = fmaxf(m0, __shfl_xor(m0, 2));
        m0 = fmaxf(m0, __shfl_xor(m0, 4));
        m0 = fmaxf(m0, __shfl_xor(m0, 8));
        mx[rr] = m0;
    }
#pragma unroll
    for (int j = 0; j < 8; ++j)
#pragma unroll
        for (int rr = 0; rr < 4; ++rr) sc[j][rr] = __expf(sc[j][rr] - mx[rr]);
#pragma unroll
    for (int rr = 0; rr < 4; ++rr) {
        float s0 = sc[0][rr];
#pragma unroll
        for (int j = 1; j < 8; ++j) s0 += sc[j][rr];
        s0 += __shfl_xor(s0, 1);
        s0 += __shfl_xor(s0, 2);
        s0 += __shfl_xor(s0, 4);
        s0 += __shfl_xor(s0, 8);
        sm[rr] = s0;
    }
    u16* Pw = Ps + w * 16 * VLD;
#pragma unroll
    for (int j = 0; j < 8; ++j)
#pragma unroll
        for (int rr = 0; rr < 4; ++rr)
            Pw[(q16 * 4 + rr) * VLD + j * 16 + l15] = f2bu(sc[j][rr]);
    f32x4 o[4] = {};
#pragma unroll
    for (int kt = 0; kt < 4; ++kt) {
        bf16x8 ap = *(const bf16x8*)(Pw + l15 * VLD + kt * 32 + q8);
#pragma unroll
        for (int j = 0; j < 4; ++j) {
            bf16x8 bv = *(const bf16x8*)(vg + (size_t)(j * 16 + l15) * LL + kc + kt * 32 + q8);
            o[j] = __builtin_amdgcn_mfma_f32_16x16x32_bf16(ap, bv, o[j], 0, 0, 0);
        }
    }
#pragma unroll
    for (int j = 0; j < 4; ++j)
#pragma unroll
        for (int rr = 0; rr < 4; ++rr)
            Osh[w][(q16 * 4 + rr) * 65 + j * 16 + l15] = o[j][rr];
    if (l15 == 0) {
#pragma unroll
        for (int rr = 0; rr < 4; ++rr) {
            Msh[w][q16 * 4 + rr] = mx[rr];
            Lsh[w][q16 * 4 + rr] = sm[rr];
        }
    }
    __syncthreads();
    int qq = t >> 4, dg = (t & 15) * 4;
    float m0 = Msh[0][qq], m1 = Msh[1][qq], m2 = Msh[2][qq], m3 = Msh[3][qq];
    float ms = fmaxf(fmaxf(m0, m1), fmaxf(m2, m3));
    float f0 = __expf(m0 - ms), f1 = __expf(m1 - ms), f2 = __expf(m2 - ms), f3 = __expf(m3 - ms);
    float lst = Lsh[0][qq] * f0 + Lsh[1][qq] * f1 + Lsh[2][qq] * f2 + Lsh[3][qq] * f3;
    float inv = 1.0f / lst;
    ushort4 res;
    u16* rp = (u16*)&res;
#pragma unroll
    for (int i = 0; i < 4; ++i) {
        int idx = qq * 65 + dg + i;
        float a = Osh[0][idx] * f0 + Osh[1][idx] * f1 + Osh[2][idx] * f2 + Osh[3][idx] * f3;
        rp[i] = f2bu(a * inv);
    }
    *(ushort4*)(head + (size_t)(b * LL + q0 + qq) * DA + dg) = res;
}

// ========== fused Toeplitz GEMM + proj + bias + gate (unchanged) ==========
__device__ __forceinline__ void mfma_tile64(const u16* As, const u16* Bs,
                                            f32x4 acc[4][4], int wm, int wn,
                                            int l15, int q16) {
    int s7 = l15 & 7;
#pragma unroll
    for (int kk = 0; kk < 2; ++kk) {
        int j0 = kk * 4 + q16;
        bf16x8 a[4], bv[4];
#pragma unroll
        for (int i = 0; i < 4; ++i) {
            int row = wm + i * 16 + l15;
            a[i] = *(const bf16x8*)(As + (row * 8 + (j0 ^ s7)) * 8);
        }
#pragma unroll
        for (int j = 0; j < 4; ++j) {
            int row = wn + j * 16 + l15;
            bv[j] = *(const bf16x8*)(Bs + (row * 8 + (j0 ^ s7)) * 8);
        }
#pragma unroll
        for (int i = 0; i < 4; ++i)
#pragma unroll
            for (int j = 0; j < 4; ++j)
                acc[i][j] = __builtin_amdgcn_mfma_f32_16x16x32_bf16(a[i], bv[j], acc[i][j], 0, 0, 0);
    }
}

__device__ __forceinline__ void stage_pair(const u16* A, const u16* B, int ldk,
                                           int koff, u16* Ad, u16* Bd, int t) {
#pragma unroll
    for (int s = 0; s < 4; ++s) {
        int ci = t + s * 256;
        int grow = ci >> 3, gcol = ((ci & 7) ^ (grow & 7)) << 3;
        async_cp16(A + (size_t)grow * ldk + koff + gcol, Ad + ci * 8);
        async_cp16(B + (size_t)grow * ldk + koff + gcol, Bd + ci * 8);
    }
}

__global__ __launch_bounds__(256, 2)
void mix_kernel(const u16* __restrict__ wt,      // [512 m][512 l]
                const u16* __restrict__ vnT,     // [B][512 c][512 l]
                const u16* __restrict__ headb,   // [B][512 m][64 d]
                const u16* __restrict__ projwT,  // [512 c][64 d]
                const float* __restrict__ x,
                const float* __restrict__ tbias,
                const float* __restrict__ projb,
                float* __restrict__ out) {
    __shared__ u16 SMEM[4][128 * 64];            // 64 KiB total (2 blk/CU)
    u16* As0 = SMEM[0]; u16* As1 = SMEM[1];
    u16* Bs0 = SMEM[2]; u16* Bs1 = SMEM[3];
    int lid = blockIdx.x;
    int p8 = lid & 7, rest = lid >> 3;
    int mi = rest & 3, pair = (rest >> 2) * 8 + p8;   // pair in [0,128)
    int b = pair >> 2, m0 = mi * 128, c0 = (pair & 3) * 128;
    int t = threadIdx.x, lane = t & 63, wid = t >> 6;
    int wm = (wid >> 1) * 64, wn = (wid & 1) * 64;
    int l15 = lane & 15, q16 = lane >> 4;
    f32x4 acc[4][4] = {};
    const u16* Ag = wt + (size_t)m0 * 512;
    const u16* Bg = vnT + ((size_t)b * H2 + c0) * 512;
    const u16* Hg = headb + ((size_t)b * LL + m0) * DA;
    const u16* Pg = projwT + (size_t)c0 * DA;

    // prologue: stage tile 0 (Toeplitz k0=0) into buf 0
    stage_pair(Ag, Bg, 512, 0, As0, Bs0, t);
    __syncthreads();                             // drains DMA

    // 9-tile pipeline: 8 Toeplitz K-slabs + proj as tile 8; stage-next ∥ MFMA-current
    for (int it = 0; it < 9; ++it) {
        int nx = it + 1;
        if (nx < 8)
            stage_pair(Ag, Bg, 512, nx * 64, (nx & 1) ? As1 : As0,
                       (nx & 1) ? Bs1 : Bs0, t);
        else if (nx == 8)
            stage_pair(Hg, Pg, 64, 0, As0, Bs0, t);
        mfma_tile64((it & 1) ? As1 : As0, (it & 1) ? Bs1 : Bs0,
                    acc, wm, wn, l15, q16);
        __syncthreads();                         // next-buf ready; cur buf released
    }

    // ---- epilogue: acc -> LDS, then streaming float4 gate pass ----
    float* Acc = (float*)&SMEM[0][0];            // 128x128 fp32 = 64 KiB exact
    int rq = q16 * 4;
#pragma unroll
    for (int i = 0; i < 4; ++i)
#pragma unroll
        for (int j = 0; j < 4; ++j)
#pragma unroll
            for (int rr = 0; rr < 4; ++rr)
                Acc[(wm + i * 16 + rq + rr) * 128 + (wn + j * 16 + l15)] = acc[i][j][rr];
    __syncthreads();
    {
        int cq = (t & 31) * 4, rg = (t >> 5) * 16;
        float4 pj = *(const float4*)(projb + c0 + cq);
#pragma unroll
        for (int rr3 = 0; rr3 < 16; ++rr3) {
            int mrow = rg + rr3;
            int m = m0 + mrow;
            float tb = tbias[m];
            float4 a4 = *(const float4*)(Acc + mrow * 128 + cq);
            float4 xv = *(const float4*)(x + ((size_t)b * LL + m) * HH + c0 + cq);
            float4 o;
            o.x = xv.x * (a4.x + tb + pj.x);
            o.y = xv.y * (a4.y + tb + pj.y);
            o.z = xv.z * (a4.z + tb + pj.z);
            o.w = xv.w * (a4.w + tb + pj.w);
            *(float4*)(out + ((size_t)b * LL + m) * H2 + c0 + cq) = o;
        }
    }
}

extern "C" void kernel_launch(void* const* d_in, const int* in_sizes, int n_in,
                              void* d_out, int out_size, void* d_ws, size_t ws_size,
                              hipStream_t stream) {
    (void)in_sizes; (void)n_in; (void)out_size; (void)ws_size;
    const float* x     = (const float*)d_in[0];
    const float* gamma = (const float*)d_in[1];
    const float* beta  = (const float*)d_in[2];
    const float* wv    = (const float*)d_in[3];
    const float* tb    = (const float*)d_in[4];
    const float* kqvw  = (const float*)d_in[5];
    const float* kqvb  = (const float*)d_in[6];
    const float* projw = (const float*)d_in[7];
    const float* projb = (const float*)d_in[8];
    float* out = (float*)d_out;

    u16* vnT_bf  = (u16*)d_ws;                          // 16 MB
    u16* qb      = vnT_bf + (size_t)NB * LL * H2;       // 2 MB
    u16* kb      = qb + (size_t)NB * LL * DA;           // 2 MB
    u16* vTb     = kb + (size_t)NB * LL * DA;           // 2 MB
    u16* head_bf = vTb + (size_t)NB * LL * DA;          // 2 MB
    u16* wt_bf   = head_bf + (size_t)NB * LL * DA;      // 512 KB
    u16* kqvwT   = wt_bf + 512 * 512;                   // 192 KB
    u16* projwT  = kqvwT + 192 * 512;                   // 64 KB

    prep_kernel <<<1536, 256, 0, stream>>>(wv, kqvw, projw, wt_bf, kqvwT, projwT);
    v_kernel    <<<256, 512, 0, stream>>>(x, kqvwT, kqvb, gamma, beta,
                                          vnT_bf, qb, kb, vTb);
    attn_kernel <<<dim3(32, NB), 256, 0, stream>>>(qb, kb, vTb, head_bf);
    mix_kernel  <<<512, 256, 0, stream>>>(wt_bf, vnT_bf, head_bf, projwT,
                                          x, tb, projb, out);
}

// Round 10
// 162.056 us; speedup vs baseline: 1.0574x; 1.0260x over previous
//
#include <hip/hip_runtime.h>
#include <math.h>

#define NB 32
#define LL 512
#define HH 1024
#define H2 512
#define DA 64

typedef unsigned int u32;
typedef unsigned short u16;
typedef __bf16 bf16x8 __attribute__((ext_vector_type(8)));
typedef float f32x4 __attribute__((ext_vector_type(4)));
typedef u16 u16x8 __attribute__((ext_vector_type(8)));

__device__ __forceinline__ u16 f2bu(float f) {          // fp32 -> bf16 bits, RNE
    u32 u = __builtin_bit_cast(u32, f);
    u = (u + 0x7fff + ((u >> 16) & 1)) >> 16;
    return (u16)u;
}

__device__ __forceinline__ float b2f(u16 u) {           // bf16 bits -> fp32
    u32 v = (u32)u << 16;
    return __builtin_bit_cast(float, v);
}

__device__ __forceinline__ void async_cp16(const void* g, void* l) {
    __builtin_amdgcn_global_load_lds(
        (const __attribute__((address_space(1))) u32*)g,
        (__attribute__((address_space(3))) u32*)l, 16, 0, 0);
}

// ========== prep: bf16 weight materialization (unchanged) ==========
__global__ void prep_kernel(const float* __restrict__ wv,
                            const float* __restrict__ kqvw,
                            const float* __restrict__ projw,
                            u16* __restrict__ wt, u16* __restrict__ kqvwT,
                            u16* __restrict__ projwT) {
    int e = blockIdx.x * 256 + threadIdx.x;
    if (e < 262144) {
        int m = e >> 9, l = e & 511;
        wt[e] = f2bu(wv[511 + m - l]);
    } else if (e < 262144 + 98304) {
        int i = e - 262144;
        int n = i >> 9, k = i & 511;
        kqvwT[i] = f2bu(kqvw[(size_t)k * 192 + n]);
    } else {
        int i = e - 360448;
        int c = i >> 6, d = i & 63;
        projwT[i] = f2bu(projw[(size_t)d * 512 + c]);
    }
}

// ========== v_kernel: R6 winner, restored verbatim ==========
// 256 blocks x 512 threads (8 waves/CU, 1 blk/CU at 112.5 KiB LDS), 64 rows
// per block. A-tile = raw bf16(v) retained in LDS; per-iteration A loads
// (2 float4/lane) ride the 8-step BK=64 pipeline; B dbuf via swizzled
// global_load_lds (49 MB aggregate); LN sums in-reg during staging.
__global__ __launch_bounds__(512, 1)
void v_kernel(const float* __restrict__ x,
              const u16* __restrict__ kqvwT, const float* __restrict__ kqvb,
              const float* __restrict__ gamma, const float* __restrict__ beta,
              u16* __restrict__ vnT,
              u16* __restrict__ qb, u16* __restrict__ kb, u16* __restrict__ vT) {
    __shared__ u16 Af[64 * 64 * 8];             // 64 KiB: row r, abs-granule g at slot g^(r&7)
    __shared__ u16 Bs_[2][192 * 64];            // 2 x 24 KiB
    __shared__ float MU[64], RS[64];
    int blk = blockIdx.x, t = threadIdx.x;
    int R0 = blk * 64, b = R0 >> 9, l0 = R0 & 511;
    int lane = t & 63, wid = t >> 6;            // wid 0..7
    int l15 = lane & 15, q16 = lane >> 4;
    int wm = (wid & 3) * 16, wn = (wid >> 2) * 96;
    const float* xg = x + (size_t)R0 * HH + H2;

    // A-stage mapping: chunk p, flat = t + p*512; row = flat>>4, f4 = flat&15
    int arow[2], af4[2], sgg[2], shalf[2];
#pragma unroll
    for (int p = 0; p < 2; ++p) {
        int flat = t + p * 512;
        arow[p] = flat >> 4; af4[p] = flat & 15;
        sgg[p] = (af4[p] >> 1) ^ (arow[p] & 7);   // swizzled granule within slab
        shalf[p] = (af4[p] & 1) * 4;
    }

    float s1[2] = {0.f, 0.f}, s2[2] = {0.f, 0.f};
    float4 av[2];
    f32x4 acc[6] = {};

    // ---- prologue: issue Bs[0]; load+accumulate+write A slab 0 ----
#pragma unroll
    for (int s = 0; s < 3; ++s) {
        int ci = t + s * 512;                   // 1536 granules: 192 rows x 8
        int grow = ci >> 3, gcol = ((ci & 7) ^ (grow & 7)) << 3;
        async_cp16(kqvwT + (size_t)grow * 512 + gcol, &Bs_[0][ci * 8]);
    }
#pragma unroll
    for (int p = 0; p < 2; ++p)
        av[p] = *(const float4*)(xg + (size_t)arow[p] * HH + af4[p] * 4);
#pragma unroll
    for (int p = 0; p < 2; ++p) {
        s1[p] += av[p].x + av[p].y + av[p].z + av[p].w;
        s2[p] += av[p].x * av[p].x + av[p].y * av[p].y
               + av[p].z * av[p].z + av[p].w * av[p].w;
        ushort4 pk;
        pk.x = f2bu(av[p].x); pk.y = f2bu(av[p].y);
        pk.z = f2bu(av[p].z); pk.w = f2bu(av[p].w);
        *(ushort4*)(&Af[(arow[p] * 64 + sgg[p]) * 8 + shalf[p]]) = pk;
    }
    __syncthreads();

    // ---- 8-step pipeline: issue next loads -> MFMA current -> write next A ----
    for (int it = 0; it < 8; ++it) {
        int nx = it + 1, nb = nx & 1, cb = it & 1;
        if (it < 7) {
            int k0n = nx * 64;
#pragma unroll
            for (int p = 0; p < 2; ++p)
                av[p] = *(const float4*)(xg + (size_t)arow[p] * HH + k0n + af4[p] * 4);
#pragma unroll
            for (int s = 0; s < 3; ++s) {
                int ci = t + s * 512;
                int grow = ci >> 3, gcol = ((ci & 7) ^ (grow & 7)) << 3;
                async_cp16(kqvwT + (size_t)grow * 512 + k0n + gcol, &Bs_[nb][ci * 8]);
            }
        }
        // MFMA on current A slab + B buffer
        const u16* Bp = &Bs_[cb][0];
#pragma unroll
        for (int kk = 0; kk < 2; ++kk) {
            int j0 = kk * 4 + q16;
            int g = it * 8 + kk * 4 + q16;
            int row = wm + l15;
            bf16x8 a = *(const bf16x8*)(&Af[(row * 64 + (g ^ (row & 7))) * 8]);
#pragma unroll
            for (int j = 0; j < 6; ++j) {
                int n = wn + j * 16 + l15;
                bf16x8 bb = *(const bf16x8*)(Bp + (n * 8 + (j0 ^ (n & 7))) * 8);
                acc[j] = __builtin_amdgcn_mfma_f32_16x16x32_bf16(a, bb, acc[j], 0, 0, 0);
            }
        }
        if (it < 7) {
#pragma unroll
            for (int p = 0; p < 2; ++p) {
                s1[p] += av[p].x + av[p].y + av[p].z + av[p].w;
                s2[p] += av[p].x * av[p].x + av[p].y * av[p].y
                       + av[p].z * av[p].z + av[p].w * av[p].w;
                ushort4 pk;
                pk.x = f2bu(av[p].x); pk.y = f2bu(av[p].y);
                pk.z = f2bu(av[p].z); pk.w = f2bu(av[p].w);
                *(ushort4*)(&Af[(arow[p] * 64 + nx * 8 + sgg[p]) * 8 + shalf[p]]) = pk;
            }
        }
        __syncthreads();
    }

    // ---- LN stats: 16-lane group reduce ----
#pragma unroll
    for (int p = 0; p < 2; ++p) {
        s1[p] += __shfl_xor(s1[p], 1); s2[p] += __shfl_xor(s2[p], 1);
        s1[p] += __shfl_xor(s1[p], 2); s2[p] += __shfl_xor(s2[p], 2);
        s1[p] += __shfl_xor(s1[p], 4); s2[p] += __shfl_xor(s2[p], 4);
        s1[p] += __shfl_xor(s1[p], 8); s2[p] += __shfl_xor(s2[p], 8);
    }
    if ((t & 15) == 0) {
#pragma unroll
        for (int p = 0; p < 2; ++p) {
            float mu = s1[p] * (1.0f / H2);
            float rstd = rsqrtf(s2[p] * (1.0f / H2) - mu * mu + 1e-5f);
            MU[arow[p]] = mu; RS[arow[p]] = rstd;
        }
    }

    // ---- epilogue A: +bias; k/q/val via LDS (alias Bs); coalesced dumps ----
    u16* Ks = &Bs_[0][0];                       // 64x64 = 4096 u16
    u16* Qs = &Bs_[0][4096];                    // 64x64 = 4096 u16
    u16* Vs = &Bs_[1][0];                       // 64x72 = 4608 u16 (pad 72)
    int rq = q16 * 4;
#pragma unroll
    for (int j = 0; j < 6; ++j) {
        int n = wn + j * 16 + l15;
        float bias = kqvb[n];
#pragma unroll
        for (int rr = 0; rr < 4; ++rr) {
            int m = wm + rq + rr;
            u16 hv = f2bu(acc[j][rr] + bias);
            if (n < 64)       Ks[m * 64 + n] = hv;
            else if (n < 128) Qs[m * 64 + (n - 64)] = hv;
            else              Vs[(n - 128) * 72 + m] = hv;
        }
    }
    __syncthreads();                            // publishes Ks/Qs/Vs + MU/RS
    {
        size_t base = (size_t)R0 * 64 + t * 8;
        *(uint4*)(kb + base) = *(const uint4*)(Ks + t * 8);
        *(uint4*)(qb + base) = *(const uint4*)(Qs + t * 8);
        int d = t >> 3, ls = (t & 7) * 8;
        *(uint4*)(vT + ((size_t)(b * 64 + d)) * 512 + l0 + ls) =
            *(const uint4*)(Vs + d * 72 + ls);
    }

    // ---- epilogue B: LN affine from Af -> vnT (1 col/thread, 64 l each) ----
    {
        int c = t;
        float ga = gamma[c], be = beta[c];
        u16* d0 = vnT + ((size_t)(b * H2 + c)) * LL + l0;
        int gbase = c >> 3, coff = c & 7;
#pragma unroll
        for (int lc = 0; lc < 8; ++lc) {
            u16x8 o0;
#pragma unroll
            for (int li = 0; li < 8; ++li) {
                int l = lc * 8 + li;
                u16 w = Af[(l * 64 + (gbase ^ (l & 7))) * 8 + coff];
                o0[li] = f2bu((b2f(w) - MU[l]) * RS[l] * ga + be);
            }
            *(u16x8*)(d0 + lc * 8) = o0;
        }
    }
}

// ========== MFMA flash attention, split-K across 4 waves (+T5 setprio) ==========
#define VLD 136
__global__ __launch_bounds__(256, 4)
void attn_kernel(const u16* __restrict__ qb, const u16* __restrict__ kb,
                 const u16* __restrict__ vT, u16* __restrict__ head) {
    __shared__ u16 Ps[4 * 16 * VLD];
    __shared__ float Osh[4][16 * 65];
    __shared__ float Msh[4][16], Lsh[4][16];
    int b = blockIdx.y, q0 = blockIdx.x * 16;
    int t = threadIdx.x, lane = t & 63, w = t >> 6;
    int l15 = lane & 15, q16 = lane >> 4, q8 = q16 * 8;
    int kc = w * 128;
    const u16* qg = qb + (size_t)b * LL * DA;
    const u16* kg = kb + (size_t)b * LL * DA;
    const u16* vg = vT + (size_t)b * DA * LL;

    bf16x8 aq[2];
#pragma unroll
    for (int s = 0; s < 2; ++s)
        aq[s] = *(const bf16x8*)(qg + (size_t)(q0 + l15) * DA + s * 32 + q8);

    f32x4 sc[8] = {};
    __builtin_amdgcn_s_setprio(1);              // T5: favor MFMA-issuing wave
#pragma unroll
    for (int j = 0; j < 8; ++j) {
#pragma unroll
        for (int s = 0; s < 2; ++s) {
            bf16x8 bk = *(const bf16x8*)(kg + (size_t)(kc + j * 16 + l15) * DA + s * 32 + q8);
            sc[j] = __builtin_amdgcn_mfma_f32_16x16x32_bf16(aq[s], bk, sc[j], 0, 0, 0);
        }
    }
    __builtin_amdgcn_s_setprio(0);
    float mx[4], sm[4];
#pragma unroll
    for (int j = 0; j < 8; ++j)
#pragma unroll
        for (int rr = 0; rr < 4; ++rr) sc[j][rr] *= 0.125f;
#pragma unroll
    for (int rr = 0; rr < 4; ++rr) {
        float m0 = sc[0][rr];
#pragma unroll
        for (int j = 1; j < 8; ++j) m0 = fmaxf(m0, sc[j][rr]);
        m0 = fmaxf(m0, __shfl_xor(m0, 1));
        m0 = fmaxf(m0, __shfl_xor(m0, 2));
        m0 = fmaxf(m0, __shfl_xor(m0, 4));
        m0 = fmaxf(m0, __shfl_xor(m0, 8));
        mx[rr] = m0;
    }
#pragma unroll
    for (int j = 0; j < 8; ++j)
#pragma unroll
        for (int rr = 0; rr < 4; ++rr) sc[j][rr] = __expf(sc[j][rr] - mx[rr]);
#pragma unroll
    for (int rr = 0; rr < 4; ++rr) {
        float s0 = sc[0][rr];
#pragma unroll
        for (int j = 1; j < 8; ++j) s0 += sc[j][rr];
        s0 += __shfl_xor(s0, 1);
        s0 += __shfl_xor(s0, 2);
        s0 += __shfl_xor(s0, 4);
        s0 += __shfl_xor(s0, 8);
        sm[rr] = s0;
    }
    u16* Pw = Ps + w * 16 * VLD;
#pragma unroll
    for (int j = 0; j < 8; ++j)
#pragma unroll
        for (int rr = 0; rr < 4; ++rr)
            Pw[(q16 * 4 + rr) * VLD + j * 16 + l15] = f2bu(sc[j][rr]);
    f32x4 o[4] = {};
    __builtin_amdgcn_s_setprio(1);              // T5: PV cluster
#pragma unroll
    for (int kt = 0; kt < 4; ++kt) {
        bf16x8 ap = *(const bf16x8*)(Pw + l15 * VLD + kt * 32 + q8);
#pragma unroll
        for (int j = 0; j < 4; ++j) {
            bf16x8 bv = *(const bf16x8*)(vg + (size_t)(j * 16 + l15) * LL + kc + kt * 32 + q8);
            o[j] = __builtin_amdgcn_mfma_f32_16x16x32_bf16(ap, bv, o[j], 0, 0, 0);
        }
    }
    __builtin_amdgcn_s_setprio(0);
#pragma unroll
    for (int j = 0; j < 4; ++j)
#pragma unroll
        for (int rr = 0; rr < 4; ++rr)
            Osh[w][(q16 * 4 + rr) * 65 + j * 16 + l15] = o[j][rr];
    if (l15 == 0) {
#pragma unroll
        for (int rr = 0; rr < 4; ++rr) {
            Msh[w][q16 * 4 + rr] = mx[rr];
            Lsh[w][q16 * 4 + rr] = sm[rr];
        }
    }
    __syncthreads();
    int qq = t >> 4, dg = (t & 15) * 4;
    float m0 = Msh[0][qq], m1 = Msh[1][qq], m2 = Msh[2][qq], m3 = Msh[3][qq];
    float ms = fmaxf(fmaxf(m0, m1), fmaxf(m2, m3));
    float f0 = __expf(m0 - ms), f1 = __expf(m1 - ms), f2 = __expf(m2 - ms), f3 = __expf(m3 - ms);
    float lst = Lsh[0][qq] * f0 + Lsh[1][qq] * f1 + Lsh[2][qq] * f2 + Lsh[3][qq] * f3;
    float inv = 1.0f / lst;
    ushort4 res;
    u16* rp = (u16*)&res;
#pragma unroll
    for (int i = 0; i < 4; ++i) {
        int idx = qq * 65 + dg + i;
        float a = Osh[0][idx] * f0 + Osh[1][idx] * f1 + Osh[2][idx] * f2 + Osh[3][idx] * f3;
        rp[i] = f2bu(a * inv);
    }
    *(ushort4*)(head + (size_t)(b * LL + q0 + qq) * DA + dg) = res;
}

// ========== fused Toeplitz GEMM + proj + bias + gate (unchanged) ==========
__device__ __forceinline__ void mfma_tile64(const u16* As, const u16* Bs,
                                            f32x4 acc[4][4], int wm, int wn,
                                            int l15, int q16) {
    int s7 = l15 & 7;
#pragma unroll
    for (int kk = 0; kk < 2; ++kk) {
        int j0 = kk * 4 + q16;
        bf16x8 a[4], bv[4];
#pragma unroll
        for (int i = 0; i < 4; ++i) {
            int row = wm + i * 16 + l15;
            a[i] = *(const bf16x8*)(As + (row * 8 + (j0 ^ s7)) * 8);
        }
#pragma unroll
        for (int j = 0; j < 4; ++j) {
            int row = wn + j * 16 + l15;
            bv[j] = *(const bf16x8*)(Bs + (row * 8 + (j0 ^ s7)) * 8);
        }
#pragma unroll
        for (int i = 0; i < 4; ++i)
#pragma unroll
            for (int j = 0; j < 4; ++j)
                acc[i][j] = __builtin_amdgcn_mfma_f32_16x16x32_bf16(a[i], bv[j], acc[i][j], 0, 0, 0);
    }
}

__device__ __forceinline__ void stage_pair(const u16* A, const u16* B, int ldk,
                                           int koff, u16* Ad, u16* Bd, int t) {
#pragma unroll
    for (int s = 0; s < 4; ++s) {
        int ci = t + s * 256;
        int grow = ci >> 3, gcol = ((ci & 7) ^ (grow & 7)) << 3;
        async_cp16(A + (size_t)grow * ldk + koff + gcol, Ad + ci * 8);
        async_cp16(B + (size_t)grow * ldk + koff + gcol, Bd + ci * 8);
    }
}

__global__ __launch_bounds__(256, 2)
void mix_kernel(const u16* __restrict__ wt,      // [512 m][512 l]
                const u16* __restrict__ vnT,     // [B][512 c][512 l]
                const u16* __restrict__ headb,   // [B][512 m][64 d]
                const u16* __restrict__ projwT,  // [512 c][64 d]
                const float* __restrict__ x,
                const float* __restrict__ tbias,
                const float* __restrict__ projb,
                float* __restrict__ out) {
    __shared__ u16 SMEM[4][128 * 64];            // 64 KiB total (2 blk/CU)
    u16* As0 = SMEM[0]; u16* As1 = SMEM[1];
    u16* Bs0 = SMEM[2]; u16* Bs1 = SMEM[3];
    int lid = blockIdx.x;
    int p8 = lid & 7, rest = lid >> 3;
    int mi = rest & 3, pair = (rest >> 2) * 8 + p8;   // pair in [0,128)
    int b = pair >> 2, m0 = mi * 128, c0 = (pair & 3) * 128;
    int t = threadIdx.x, lane = t & 63, wid = t >> 6;
    int wm = (wid >> 1) * 64, wn = (wid & 1) * 64;
    int l15 = lane & 15, q16 = lane >> 4;
    f32x4 acc[4][4] = {};
    const u16* Ag = wt + (size_t)m0 * 512;
    const u16* Bg = vnT + ((size_t)b * H2 + c0) * 512;
    const u16* Hg = headb + ((size_t)b * LL + m0) * DA;
    const u16* Pg = projwT + (size_t)c0 * DA;

    // prologue: stage tile 0 (Toeplitz k0=0) into buf 0
    stage_pair(Ag, Bg, 512, 0, As0, Bs0, t);
    __syncthreads();                             // drains DMA

    // 9-tile pipeline: 8 Toeplitz K-slabs + proj as tile 8; stage-next ∥ MFMA-current
    for (int it = 0; it < 9; ++it) {
        int nx = it + 1;
        if (nx < 8)
            stage_pair(Ag, Bg, 512, nx * 64, (nx & 1) ? As1 : As0,
                       (nx & 1) ? Bs1 : Bs0, t);
        else if (nx == 8)
            stage_pair(Hg, Pg, 64, 0, As0, Bs0, t);
        mfma_tile64((it & 1) ? As1 : As0, (it & 1) ? Bs1 : Bs0,
                    acc, wm, wn, l15, q16);
        __syncthreads();                         // next-buf ready; cur buf released
    }

    // ---- epilogue: acc -> LDS, then streaming float4 gate pass ----
    float* Acc = (float*)&SMEM[0][0];            // 128x128 fp32 = 64 KiB exact
    int rq = q16 * 4;
#pragma unroll
    for (int i = 0; i < 4; ++i)
#pragma unroll
        for (int j = 0; j < 4; ++j)
#pragma unroll
            for (int rr = 0; rr < 4; ++rr)
                Acc[(wm + i * 16 + rq + rr) * 128 + (wn + j * 16 + l15)] = acc[i][j][rr];
    __syncthreads();
    {
        int cq = (t & 31) * 4, rg = (t >> 5) * 16;
        float4 pj = *(const float4*)(projb + c0 + cq);
#pragma unroll
        for (int rr3 = 0; rr3 < 16; ++rr3) {
            int mrow = rg + rr3;
            int m = m0 + mrow;
            float tb = tbias[m];
            float4 a4 = *(const float4*)(Acc + mrow * 128 + cq);
            float4 xv = *(const float4*)(x + ((size_t)b * LL + m) * HH + c0 + cq);
            float4 o;
            o.x = xv.x * (a4.x + tb + pj.x);
            o.y = xv.y * (a4.y + tb + pj.y);
            o.z = xv.z * (a4.z + tb + pj.z);
            o.w = xv.w * (a4.w + tb + pj.w);
            *(float4*)(out + ((size_t)b * LL + m) * H2 + c0 + cq) = o;
        }
    }
}

extern "C" void kernel_launch(void* const* d_in, const int* in_sizes, int n_in,
                              void* d_out, int out_size, void* d_ws, size_t ws_size,
                              hipStream_t stream) {
    (void)in_sizes; (void)n_in; (void)out_size; (void)ws_size;
    const float* x     = (const float*)d_in[0];
    const float* gamma = (const float*)d_in[1];
    const float* beta  = (const float*)d_in[2];
    const float* wv    = (const float*)d_in[3];
    const float* tb    = (const float*)d_in[4];
    const float* kqvw  = (const float*)d_in[5];
    const float* kqvb  = (const float*)d_in[6];
    const float* projw = (const float*)d_in[7];
    const float* projb = (const float*)d_in[8];
    float* out = (float*)d_out;

    u16* vnT_bf  = (u16*)d_ws;                          // 16 MB
    u16* qb      = vnT_bf + (size_t)NB * LL * H2;       // 2 MB
    u16* kb      = qb + (size_t)NB * LL * DA;           // 2 MB
    u16* vTb     = kb + (size_t)NB * LL * DA;           // 2 MB
    u16* head_bf = vTb + (size_t)NB * LL * DA;          // 2 MB
    u16* wt_bf   = head_bf + (size_t)NB * LL * DA;      // 512 KB
    u16* kqvwT   = wt_bf + 512 * 512;                   // 192 KB
    u16* projwT  = kqvwT + 192 * 512;                   // 64 KB

    prep_kernel <<<1536, 256, 0, stream>>>(wv, kqvw, projw, wt_bf, kqvwT, projwT);
    v_kernel    <<<256, 512, 0, stream>>>(x, kqvwT, kqvb, gamma, beta,
                                          vnT_bf, qb, kb, vTb);
    attn_kernel <<<dim3(32, NB), 256, 0, stream>>>(qb, kb, vTb, head_bf);
    mix_kernel  <<<512, 256, 0, stream>>>(wt_bf, vnT_bf, head_bf, projwT,
                                          x, tb, projb, out);
}